// Round 8
// baseline (329.898 us; speedup 1.0000x reference)
//
#include <hip/hip_runtime.h>
#include <hip/hip_cooperative_groups.h>
#include <math.h>

namespace cg = cooperative_groups;

#define NNODES 10000
#define NEDGES 320000
#define ETOT   (NEDGES + NNODES)
#define FINF   512
#define HD     512     // H*D
#define MAXDEG 128

typedef __attribute__((ext_vector_type(8))) _Float16 f16x8;
typedef __attribute__((ext_vector_type(8))) ushort u16x8;
typedef __attribute__((ext_vector_type(4))) float f32x4;

__device__ __forceinline__ ushort f2h(float f) {
    return __builtin_bit_cast(ushort, (_Float16)f);
}
__device__ __forceinline__ float h2f(ushort u) {
    return (float)__builtin_bit_cast(_Float16, u);
}

// ---------------- prep: transpose 4 weights to fp16 [N][K] ----------------
#define PW1 (512 * 512)                  // w_conv
#define PW2 (PW1 + 256 * 512)            // w_a
#define PW3 (PW2 + 128 * 256)            // w_1
#define PW4 (PW3 + 64 * 128)             // w_2
__global__ __launch_bounds__(256) void prep_kernel(
    const float* __restrict__ wc, ushort* __restrict__ wch,
    const float* __restrict__ wa, ushort* __restrict__ wah,
    const float* __restrict__ w1, ushort* __restrict__ w1h,
    const float* __restrict__ w2, ushort* __restrict__ w2h)
{
    int idx = blockIdx.x * 256 + threadIdx.x;
    if (idx >= PW4) return;
    float v; ushort* th; int i;
    if (idx < PW1) {            // w_conv [512][512] -> T
        i = idx; int n = i >> 9, k = i & 511;
        v = wc[(size_t)k * 512 + n]; th = wch;
    } else if (idx < PW2) {     // w_a [512][256] -> [256][512]
        i = idx - PW1; int n = i >> 9, k = i & 511;
        v = wa[(size_t)k * 256 + n]; th = wah;
    } else if (idx < PW3) {     // w_1 [256][128] -> [128][256]
        i = idx - PW2; int n = i >> 8, k = i & 255;
        v = w1[(size_t)k * 128 + n]; th = w1h;
    } else {                    // w_2 [128][64] -> [64][128]
        i = idx - PW3; int n = i >> 7, k = i & 127;
        v = w2[(size_t)k * 64 + n]; th = w2h;
    }
    th[i] = f2h(v);
}

// ---------------- GEMM1: h = fp16(x) @ w_conv^T, fused attn coefficients -------------
// M=NNODES, N=512, K=512. BM=64, BN=128. 4 waves 2x2; MR=2, NR=4. h out fp16.
__global__ __launch_bounds__(256) void gemm1_kernel(
    const float* __restrict__ x, const ushort* __restrict__ Bh,
    ushort* __restrict__ hout,
    const float* __restrict__ att_s, const float* __restrict__ att_d,
    float* __restrict__ a_src, float* __restrict__ a_dst)
{
    constexpr int MR = 2, NR = 4;
    __shared__ ushort sA[64][40], sB[128][40];
    int tid = threadIdx.x;
    int lane = tid & 63, wave = tid >> 6;
    int wr = wave >> 1, wcj = wave & 1;
    int bm = blockIdx.y * 64, bn = blockIdx.x * 128;
    int mrow = lane & 15, kb = lane >> 4;

    int ar = tid >> 2, akc = tid & 3;
    int arow = bm + ar;
    bool aval = arow < NNODES;
    size_t aoff = (size_t)(aval ? arow : 0) * FINF + akc * 8;
    int br = tid >> 1, bkc = (tid & 1) * 2;
    size_t boff = (size_t)(bn + br) * FINF + bkc * 8;

    f32x4 acc[MR][NR];
    #pragma unroll
    for (int i = 0; i < MR; ++i)
        #pragma unroll
        for (int j = 0; j < NR; ++j)
            acc[i][j] = (f32x4){0.f, 0.f, 0.f, 0.f};

    for (int k0 = 0; k0 < FINF; k0 += 32) {
        u16x8 us = (u16x8)0;
        if (aval) {
            const float* ap = x + aoff + k0;
            float4 f0 = *(const float4*)ap;
            float4 f1 = *(const float4*)(ap + 4);
            us[0] = f2h(f0.x); us[1] = f2h(f0.y); us[2] = f2h(f0.z); us[3] = f2h(f0.w);
            us[4] = f2h(f1.x); us[5] = f2h(f1.y); us[6] = f2h(f1.z); us[7] = f2h(f1.w);
        }
        int4 va = __builtin_bit_cast(int4, us);
        int4 vb0 = *(const int4*)(Bh + boff + k0);
        int4 vb1 = *(const int4*)(Bh + boff + k0 + 8);
        __syncthreads();
        *(int4*)&sA[ar][akc * 8] = va;
        *(int4*)&sB[br][bkc * 8] = vb0;
        *(int4*)&sB[br][(bkc + 1) * 8] = vb1;
        __syncthreads();

        f16x8 fa[MR], fb[NR];
        #pragma unroll
        for (int fi = 0; fi < MR; ++fi)
            fa[fi] = *(const f16x8*)&sA[wr * 32 + fi * 16 + mrow][kb * 8];
        #pragma unroll
        for (int fj = 0; fj < NR; ++fj)
            fb[fj] = *(const f16x8*)&sB[wcj * 64 + fj * 16 + mrow][kb * 8];
        #pragma unroll
        for (int fi = 0; fi < MR; ++fi)
            #pragma unroll
            for (int fj = 0; fj < NR; ++fj)
                acc[fi][fj] = __builtin_amdgcn_mfma_f32_16x16x32_f16(fa[fi], fb[fj], acc[fi][fj], 0, 0, 0);
    }

    // write h fp16
    #pragma unroll
    for (int fi = 0; fi < MR; ++fi) {
        int crow0 = bm + wr * 32 + fi * 16 + (lane >> 4) * 4;
        #pragma unroll
        for (int fj = 0; fj < NR; ++fj) {
            int ccol = bn + wcj * 64 + fj * 16 + mrow;
            #pragma unroll
            for (int r = 0; r < 4; ++r) {
                int row = crow0 + r;
                if (row < NNODES)
                    hout[(size_t)row * HD + ccol] = f2h(acc[fi][fj][r]);
            }
        }
    }

    // attn coefficients: a_src[row,hd] += sum_cols h*att  (block cols in one head)
    int hd = bn >> 8;
    float as_v[NR], ad_v[NR];
    #pragma unroll
    for (int fj = 0; fj < NR; ++fj) {
        int c = bn + wcj * 64 + fj * 16 + mrow;
        as_v[fj] = att_s[c];
        ad_v[fj] = att_d[c];
    }
    #pragma unroll
    for (int fi = 0; fi < MR; ++fi)
        #pragma unroll
        for (int r = 0; r < 4; ++r) {
            float ss = 0.f, sd = 0.f;
            #pragma unroll
            for (int fj = 0; fj < NR; ++fj) {
                float v = acc[fi][fj][r];
                ss = fmaf(v, as_v[fj], ss);
                sd = fmaf(v, ad_v[fj], sd);
            }
            #pragma unroll
            for (int off = 1; off < 16; off <<= 1) {
                ss += __shfl_xor(ss, off);
                sd += __shfl_xor(sd, off);
            }
            if (mrow == 0) {
                int row = bm + wr * 32 + fi * 16 + (lane >> 4) * 4 + r;
                if (row < NNODES) {
                    atomicAdd(&a_src[2 * row + hd], ss);
                    atomicAdd(&a_dst[2 * row + hd], sd);
                }
            }
        }
}

// ---------------- scatter edges into fixed-stride buckets; p = exp(lrelu(e)) ----------
__global__ __launch_bounds__(256) void scatter_kernel(const int* __restrict__ ei,
    const float* __restrict__ a_src, const float* __restrict__ a_dst,
    int* __restrict__ cnt, int* __restrict__ esrc,
    float* __restrict__ p0, float* __restrict__ p1)
{
    int e = blockIdx.x * 256 + threadIdx.x;
    if (e >= ETOT) return;
    int s, d;
    if (e < NEDGES) { s = ei[e]; d = ei[NEDGES + e]; } else { s = d = e - NEDGES; }
    int pos = atomicAdd(&cnt[d], 1);
    if (pos >= MAXDEG) return;   // statistically impossible for this graph
    int slot = d * MAXDEG + pos;
    esrc[slot] = s;
    float e0 = a_src[2 * s] + a_dst[2 * d];
    e0 = (e0 > 0.f) ? e0 : 0.2f * e0;
    float e1 = a_src[2 * s + 1] + a_dst[2 * d + 1];
    e1 = (e1 > 0.f) ? e1 : 0.2f * e1;
    p0[slot] = expf(e0);
    p1[slot] = expf(e1);
}

// ---------------- per-node aggregation (fp16 h) -> lrelu -> fp16 y ----------------
__global__ __launch_bounds__(128) void aggregate_kernel(const ushort* __restrict__ h,
    const int* __restrict__ cnt, const int* __restrict__ esrc,
    const float* __restrict__ p0, const float* __restrict__ p1,
    const float* __restrict__ b_conv, ushort* __restrict__ yh)
{
    int n = blockIdx.x, t = threadIdx.x;
    int len = cnt[n]; if (len > MAXDEG) len = MAXDEG;
    int base = n * MAXDEG;
    const float* pp = (t < 64) ? p0 : p1;
    float a0 = 0.f, a1 = 0.f, a2 = 0.f, a3 = 0.f;
    float den = 0.f;
    for (int k = 0; k < len; ++k) {
        int src = esrc[base + k];
        float q = pp[base + k];
        ushort4 hv = ((const ushort4*)(h + (size_t)src * HD))[t];
        a0 = fmaf(q, h2f(hv.x), a0);
        a1 = fmaf(q, h2f(hv.y), a1);
        a2 = fmaf(q, h2f(hv.z), a2);
        a3 = fmaf(q, h2f(hv.w), a3);
        den += q;
    }
    float4 bc = *(const float4*)(b_conv + t * 4);
    float inv = 1.f / den;
    float o[4] = { a0 * inv + bc.x, a1 * inv + bc.y, a2 * inv + bc.z, a3 * inv + bc.w };
    ushort4 hq;
    float v;
    v = (o[0] > 0.f) ? o[0] : 0.01f * o[0]; hq.x = f2h(v);
    v = (o[1] > 0.f) ? o[1] : 0.01f * o[1]; hq.y = f2h(v);
    v = (o[2] > 0.f) ? o[2] : 0.01f * o[2]; hq.z = f2h(v);
    v = (o[3] > 0.f) ? o[3] : 0.01f * o[3]; hq.w = f2h(v);
    ((ushort4*)(yh + (size_t)n * HD))[t] = hq;
}

// ---------------- cooperative tail: densea+BN+dense1+BN+dense2+BN+dense3 -------------
// 157 blocks x 256 threads; block owns 64 rows end-to-end; grid.sync at stat barriers.
__global__ __launch_bounds__(256) void tail_kernel(
    const ushort* __restrict__ yh,
    const ushort* __restrict__ wah, const ushort* __restrict__ w1h,
    const ushort* __restrict__ w2h,
    const float* __restrict__ g_a, const float* __restrict__ be_a,
    const float* __restrict__ g_1, const float* __restrict__ be_1,
    const float* __restrict__ g_2, const float* __restrict__ be_2,
    const float* __restrict__ w3, const float* __restrict__ b3,
    float* __restrict__ stA, float* __restrict__ st1, float* __restrict__ st2,
    float* __restrict__ y3)
{
    cg::grid_group grid = cg::this_grid();
    __shared__ __align__(16) char smem[61440];
    ushort (*sAct)[264]  = (ushort(*)[264])smem;                  // 64x264 fp16 (33792 B)
    ushort (*sAct2)[136] = (ushort(*)[136])smem;                  // reuse (17408 B)
    float  (*act3)[68]   = (float(*)[68])smem;                    // reuse (17408 B)
    ushort (*sA)[40] = (ushort(*)[40])(smem + 33792);             // 64x40 (5120 B)
    ushort (*sB)[40] = (ushort(*)[40])(smem + 33792 + 5120);      // 256x40 (20480 B)
    float* bsc = (float*)(smem + 59392);
    float* bsh = bsc + 256;

    const int tid = threadIdx.x;
    const int lane = tid & 63, wave = tid >> 6;
    const int wr = wave >> 1, wcj = wave & 1;
    const int mrow = lane & 15, kb = lane >> 4;
    const int bm = blockIdx.x * 64;
    const int rbase = wr * 32 + (lane >> 4) * 4;
    const int ar = tid >> 2, akc = tid & 3;

    // ======== Phase A: z_a = yh @ wah^T  (64 x 256, K=512) ========
    f32x4 accA[2][8];
    #pragma unroll
    for (int i = 0; i < 2; ++i)
        #pragma unroll
        for (int j = 0; j < 8; ++j)
            accA[i][j] = (f32x4){0.f, 0.f, 0.f, 0.f};
    {
        int arow = bm + ar;
        bool aval = arow < NNODES;
        const ushort* aptr = yh + (size_t)(aval ? arow : 0) * 512 + akc * 8;
        for (int k0 = 0; k0 < 512; k0 += 32) {
            int4 va = aval ? *(const int4*)(aptr + k0) : (int4){0, 0, 0, 0};
            int4 vb[4];
            #pragma unroll
            for (int p = 0; p < 4; ++p)
                vb[p] = *(const int4*)(wah + (size_t)(ar + p * 64) * 512 + k0 + akc * 8);
            __syncthreads();
            *(int4*)&sA[ar][akc * 8] = va;
            #pragma unroll
            for (int p = 0; p < 4; ++p)
                *(int4*)&sB[ar + p * 64][akc * 8] = vb[p];
            __syncthreads();
            f16x8 fa[2], fb[8];
            #pragma unroll
            for (int fi = 0; fi < 2; ++fi)
                fa[fi] = *(const f16x8*)&sA[wr * 32 + fi * 16 + mrow][kb * 8];
            #pragma unroll
            for (int fj = 0; fj < 8; ++fj)
                fb[fj] = *(const f16x8*)&sB[wcj * 128 + fj * 16 + mrow][kb * 8];
            #pragma unroll
            for (int fi = 0; fi < 2; ++fi)
                #pragma unroll
                for (int fj = 0; fj < 8; ++fj)
                    accA[fi][fj] = __builtin_amdgcn_mfma_f32_16x16x32_f16(fa[fi], fb[fj], accA[fi][fj], 0, 0, 0);
        }
    }
    // stats -> stA
    #pragma unroll
    for (int fj = 0; fj < 8; ++fj) {
        float s = 0.f, s2 = 0.f;
        #pragma unroll
        for (int fi = 0; fi < 2; ++fi)
            #pragma unroll
            for (int r = 0; r < 4; ++r) {
                float v = accA[fi][fj][r];
                s += v; s2 = fmaf(v, v, s2);
            }
        s  += __shfl_xor(s, 16);  s  += __shfl_xor(s, 32);
        s2 += __shfl_xor(s2, 16); s2 += __shfl_xor(s2, 32);
        if (lane < 16) {
            int c = wcj * 128 + fj * 16 + lane;
            atomicAdd(&stA[c], s);
            atomicAdd(&stA[256 + c], s2);
        }
    }
    grid.sync();
    {
        int c = tid;   // 256 cols
        float s  = atomicAdd(&stA[c], 0.f);
        float s2 = atomicAdd(&stA[256 + c], 0.f);
        float m = s * (1.f / NNODES);
        float var = s2 * (1.f / NNODES) - m * m;
        float sc = g_a[c] * rsqrtf(var + 1e-5f);
        bsc[c] = sc; bsh[c] = be_a[c] - m * sc;
    }
    __syncthreads();
    #pragma unroll
    for (int fi = 0; fi < 2; ++fi)
        #pragma unroll
        for (int fj = 0; fj < 8; ++fj) {
            int c = wcj * 128 + fj * 16 + mrow;
            #pragma unroll
            for (int r = 0; r < 4; ++r) {
                int rr = rbase + fi * 16 + r;
                float v = fmaf(accA[fi][fj][r], bsc[c], bsh[c]);
                v = (v > 0.f) ? v : 0.01f * v;
                if (bm + rr >= NNODES) v = 0.f;
                sAct[rr][c] = f2h(v);
            }
        }
    __syncthreads();

    // ======== Phase B: z1 = act @ w1h^T  (64 x 128, K=256) ========
    f32x4 accB[2][4];
    #pragma unroll
    for (int i = 0; i < 2; ++i)
        #pragma unroll
        for (int j = 0; j < 4; ++j)
            accB[i][j] = (f32x4){0.f, 0.f, 0.f, 0.f};
    for (int k0 = 0; k0 < 256; k0 += 32) {
        int4 vb[2];
        #pragma unroll
        for (int p = 0; p < 2; ++p)
            vb[p] = *(const int4*)(w1h + (size_t)(ar + p * 64) * 256 + k0 + akc * 8);
        __syncthreads();
        #pragma unroll
        for (int p = 0; p < 2; ++p)
            *(int4*)&sB[ar + p * 64][akc * 8] = vb[p];
        __syncthreads();
        f16x8 fa[2], fb[4];
        #pragma unroll
        for (int fi = 0; fi < 2; ++fi)
            fa[fi] = *(const f16x8*)&sAct[wr * 32 + fi * 16 + mrow][k0 + kb * 8];
        #pragma unroll
        for (int fj = 0; fj < 4; ++fj)
            fb[fj] = *(const f16x8*)&sB[wcj * 64 + fj * 16 + mrow][kb * 8];
        #pragma unroll
        for (int fi = 0; fi < 2; ++fi)
            #pragma unroll
            for (int fj = 0; fj < 4; ++fj)
                accB[fi][fj] = __builtin_amdgcn_mfma_f32_16x16x32_f16(fa[fi], fb[fj], accB[fi][fj], 0, 0, 0);
    }
    #pragma unroll
    for (int fj = 0; fj < 4; ++fj) {
        float s = 0.f, s2 = 0.f;
        #pragma unroll
        for (int fi = 0; fi < 2; ++fi)
            #pragma unroll
            for (int r = 0; r < 4; ++r) {
                float v = accB[fi][fj][r];
                s += v; s2 = fmaf(v, v, s2);
            }
        s  += __shfl_xor(s, 16);  s  += __shfl_xor(s, 32);
        s2 += __shfl_xor(s2, 16); s2 += __shfl_xor(s2, 32);
        if (lane < 16) {
            int c = wcj * 64 + fj * 16 + lane;
            atomicAdd(&st1[c], s);
            atomicAdd(&st1[128 + c], s2);
        }
    }
    grid.sync();
    if (tid < 128) {
        int c = tid;
        float s  = atomicAdd(&st1[c], 0.f);
        float s2 = atomicAdd(&st1[128 + c], 0.f);
        float m = s * (1.f / NNODES);
        float var = s2 * (1.f / NNODES) - m * m;
        float sc = g_1[c] * rsqrtf(var + 1e-5f);
        bsc[c] = sc; bsh[c] = be_1[c] - m * sc;
    }
    __syncthreads();
    #pragma unroll
    for (int fi = 0; fi < 2; ++fi)
        #pragma unroll
        for (int fj = 0; fj < 4; ++fj) {
            int c = wcj * 64 + fj * 16 + mrow;
            #pragma unroll
            for (int r = 0; r < 4; ++r) {
                int rr = rbase + fi * 16 + r;
                float v = fmaf(accB[fi][fj][r], bsc[c], bsh[c]);
                v = (v > 0.f) ? v : 0.01f * v;
                if (bm + rr >= NNODES) v = 0.f;
                sAct2[rr][c] = f2h(v);
            }
        }
    __syncthreads();

    // ======== Phase C: z2 = act2 @ w2h^T  (64 x 64, K=128) ========
    f32x4 accC[2][2];
    #pragma unroll
    for (int i = 0; i < 2; ++i)
        #pragma unroll
        for (int j = 0; j < 2; ++j)
            accC[i][j] = (f32x4){0.f, 0.f, 0.f, 0.f};
    for (int k0 = 0; k0 < 128; k0 += 32) {
        int4 vb = *(const int4*)(w2h + (size_t)ar * 128 + k0 + akc * 8);
        __syncthreads();
        *(int4*)&sB[ar][akc * 8] = vb;
        __syncthreads();
        f16x8 fa[2], fb[2];
        #pragma unroll
        for (int fi = 0; fi < 2; ++fi)
            fa[fi] = *(const f16x8*)&sAct2[wr * 32 + fi * 16 + mrow][k0 + kb * 8];
        #pragma unroll
        for (int fj = 0; fj < 2; ++fj)
            fb[fj] = *(const f16x8*)&sB[wcj * 32 + fj * 16 + mrow][kb * 8];
        #pragma unroll
        for (int fi = 0; fi < 2; ++fi)
            #pragma unroll
            for (int fj = 0; fj < 2; ++fj)
                accC[fi][fj] = __builtin_amdgcn_mfma_f32_16x16x32_f16(fa[fi], fb[fj], accC[fi][fj], 0, 0, 0);
    }
    #pragma unroll
    for (int fj = 0; fj < 2; ++fj) {
        float s = 0.f, s2 = 0.f;
        #pragma unroll
        for (int fi = 0; fi < 2; ++fi)
            #pragma unroll
            for (int r = 0; r < 4; ++r) {
                float v = accC[fi][fj][r];
                s += v; s2 = fmaf(v, v, s2);
            }
        s  += __shfl_xor(s, 16);  s  += __shfl_xor(s, 32);
        s2 += __shfl_xor(s2, 16); s2 += __shfl_xor(s2, 32);
        if (lane < 16) {
            int c = wcj * 32 + fj * 16 + lane;
            atomicAdd(&st2[c], s);
            atomicAdd(&st2[64 + c], s2);
        }
    }
    grid.sync();
    if (tid < 64) {
        int c = tid;
        float s  = atomicAdd(&st2[c], 0.f);
        float s2 = atomicAdd(&st2[64 + c], 0.f);
        float m = s * (1.f / NNODES);
        float var = s2 * (1.f / NNODES) - m * m;
        float sc = g_2[c] * rsqrtf(var + 1e-5f);
        bsc[c] = sc; bsh[c] = be_2[c] - m * sc;
    }
    __syncthreads();
    // ======== Phase D: BN + lrelu + dense3 -> y3 ========
    #pragma unroll
    for (int fi = 0; fi < 2; ++fi)
        #pragma unroll
        for (int fj = 0; fj < 2; ++fj) {
            int c = wcj * 32 + fj * 16 + mrow;
            #pragma unroll
            for (int r = 0; r < 4; ++r) {
                int rr = rbase + fi * 16 + r;
                float v = fmaf(accC[fi][fj][r], bsc[c], bsh[c]);
                v = (v > 0.f) ? v : 0.01f * v;
                act3[rr][c] = v;
            }
        }
    __syncthreads();
    if (tid < 64) {
        int row = bm + tid;
        if (row < NNODES) {
            float o0 = b3[0], o1 = b3[1], o2 = b3[2];
            #pragma unroll
            for (int c = 0; c < 64; ++c) {
                float v = act3[tid][c];
                o0 = fmaf(v, w3[3 * c],     o0);
                o1 = fmaf(v, w3[3 * c + 1], o1);
                o2 = fmaf(v, w3[3 * c + 2], o2);
            }
            y3[3 * row] = o0; y3[3 * row + 1] = o1; y3[3 * row + 2] = o2;
        }
    }
}

// ---------------- pairwise euclidean distances [N,N], 4 cols/thread, NT f32x4 stores ----
__global__ __launch_bounds__(256) void dist_kernel(const float* __restrict__ y3, float* __restrict__ out)
{
    int j0 = (blockIdx.x * 256 + threadIdx.x) * 4;
    int i0 = blockIdx.y * 64;
    if (j0 >= NNODES) return;
    const float4* yp = (const float4*)(y3 + 3 * j0);
    float4 q0 = yp[0], q1 = yp[1], q2 = yp[2];
    float xj[4] = {q0.x, q0.w, q1.z, q2.y};
    float yj[4] = {q0.y, q1.x, q1.w, q2.z};
    float zj[4] = {q0.z, q1.y, q2.x, q2.w};
    int iend = (i0 + 64 < NNODES) ? (i0 + 64) : NNODES;
    for (int i = i0; i < iend; ++i) {
        float xi = y3[3 * i], yi = y3[3 * i + 1], zi = y3[3 * i + 2];
        f32x4 dv;
        #pragma unroll
        for (int u = 0; u < 4; ++u) {
            float dx = xi - xj[u], dy = yi - yj[u], dz = zi - zj[u];
            float d2 = fmaf(dx, dx, fmaf(dy, dy, dz * dz));
            dv[u] = (d2 > 1e-12f) ? sqrtf(d2) : 0.f;
        }
        __builtin_nontemporal_store(dv, (f32x4*)(out + (size_t)i * NNODES + j0));
    }
}

extern "C" void kernel_launch(void* const* d_in, const int* in_sizes, int n_in,
                              void* d_out, int out_size, void* d_ws, size_t ws_size,
                              hipStream_t stream)
{
    (void)in_sizes; (void)n_in; (void)out_size; (void)ws_size;
    const float* x      = (const float*)d_in[0];
    const int*   ei     = (const int*)  d_in[1];
    const float* w_conv = (const float*)d_in[2];
    const float* att_s  = (const float*)d_in[3];
    const float* att_d  = (const float*)d_in[4];
    const float* b_conv = (const float*)d_in[5];
    const float* w_a  = (const float*)d_in[6];
    const float* g_a  = (const float*)d_in[8];
    const float* be_a = (const float*)d_in[9];
    const float* w_1  = (const float*)d_in[10];
    const float* g_1  = (const float*)d_in[12];
    const float* be_1 = (const float*)d_in[13];
    const float* w_2  = (const float*)d_in[14];
    const float* g_2  = (const float*)d_in[16];
    const float* be_2 = (const float*)d_in[17];
    const float* w_3  = (const float*)d_in[18];
    const float* b_3  = (const float*)d_in[19];

    char* ws = (char*)d_ws;
    size_t off = 0;
    auto take = [&](size_t bytes) {
        char* p = ws + off;
        off = (off + bytes + 255) & ~(size_t)255;
        return p;
    };
    ushort* h    = (ushort*)take((size_t)NNODES * HD * 2);     // fp16 h
    ushort* yh   = (ushort*)take((size_t)NNODES * HD * 2);     // fp16 y
    float*  y3   = (float*)take((size_t)NNODES * 3 * 4);
    ushort* wch  = (ushort*)take((size_t)512 * 512 * 2);
    ushort* wah  = (ushort*)take((size_t)256 * 512 * 2);
    ushort* w1h  = (ushort*)take((size_t)128 * 256 * 2);
    ushort* w2h  = (ushort*)take((size_t)64 * 128 * 2);
    int*    esrc = (int*)  take((size_t)NNODES * MAXDEG * 4);
    float*  p0   = (float*)take((size_t)NNODES * MAXDEG * 4);
    float*  p1   = (float*)take((size_t)NNODES * MAXDEG * 4);
    // zeroed block: cnt, stats x3, a_src, a_dst
    const size_t ZB = 40000 + 2048 + 1024 + 512 + 80000 + 80000;
    char*  zblk = take(ZB);
    int*   cnt  = (int*)(zblk);
    float* stA  = (float*)(zblk + 40000);
    float* st1  = (float*)(zblk + 42048);
    float* st2  = (float*)(zblk + 43072);
    float* a_src= (float*)(zblk + 43584);
    float* a_dst= (float*)(zblk + 123584);

    hipMemsetAsync(zblk, 0, ZB, stream);

    dim3 b256(256), b128(128);
    const int MT = (NNODES + 63) / 64;   // 157

    prep_kernel<<<dim3((PW4 + 255) / 256), b256, 0, stream>>>(
        w_conv, wch, w_a, wah, w_1, w1h, w_2, w2h);

    gemm1_kernel<<<dim3(HD / 128, MT), b256, 0, stream>>>(
        x, wch, h, att_s, att_d, a_src, a_dst);

    scatter_kernel<<<dim3((ETOT + 255) / 256), b256, 0, stream>>>(
        ei, a_src, a_dst, cnt, esrc, p0, p1);

    aggregate_kernel<<<dim3(NNODES), b128, 0, stream>>>(
        h, cnt, esrc, p0, p1, b_conv, yh);

    // cooperative tail
    {
        void* targs[] = {
            (void*)&yh, (void*)&wah, (void*)&w1h, (void*)&w2h,
            (void*)&g_a, (void*)&be_a, (void*)&g_1, (void*)&be_1,
            (void*)&g_2, (void*)&be_2, (void*)&w_3, (void*)&b_3,
            (void*)&stA, (void*)&st1, (void*)&st2, (void*)&y3
        };
        hipLaunchCooperativeKernel(reinterpret_cast<const void*>(tail_kernel),
                                   dim3(MT), dim3(256), targs, 0, stream);
    }

    dist_kernel<<<dim3((NNODES + 1023) / 1024, (NNODES + 63) / 64), b256, 0, stream>>>(
        y3, (float*)d_out);
}

// Round 9
// 263.038 us; speedup vs baseline: 1.2542x; 1.2542x over previous
//
#include <hip/hip_runtime.h>
#include <math.h>

#define NNODES 10000
#define NEDGES 320000
#define ETOT   (NEDGES + NNODES)
#define FINF   512
#define HD     512     // H*D
#define MAXDEG 128

typedef __attribute__((ext_vector_type(8))) _Float16 f16x8;
typedef __attribute__((ext_vector_type(8))) ushort u16x8;
typedef __attribute__((ext_vector_type(4))) float f32x4;

__device__ __forceinline__ ushort f2h(float f) {
    return __builtin_bit_cast(ushort, (_Float16)f);
}
__device__ __forceinline__ float h2f(ushort u) {
    return (float)__builtin_bit_cast(_Float16, u);
}

// ---------------- prep: transpose 4 weights to fp16 [N][K] ----------------
#define PW1 (512 * 512)                  // w_conv
#define PW2 (PW1 + 256 * 512)            // w_a
#define PW3 (PW2 + 128 * 256)            // w_1
#define PW4 (PW3 + 64 * 128)             // w_2
__global__ __launch_bounds__(256) void prep_kernel(
    const float* __restrict__ wc, ushort* __restrict__ wch,
    const float* __restrict__ wa, ushort* __restrict__ wah,
    const float* __restrict__ w1, ushort* __restrict__ w1h,
    const float* __restrict__ w2, ushort* __restrict__ w2h)
{
    int idx = blockIdx.x * 256 + threadIdx.x;
    if (idx >= PW4) return;
    float v; ushort* th; int i;
    if (idx < PW1) {            // w_conv [512][512] -> T
        i = idx; int n = i >> 9, k = i & 511;
        v = wc[(size_t)k * 512 + n]; th = wch;
    } else if (idx < PW2) {     // w_a [512][256] -> [256][512]
        i = idx - PW1; int n = i >> 9, k = i & 511;
        v = wa[(size_t)k * 256 + n]; th = wah;
    } else if (idx < PW3) {     // w_1 [256][128] -> [128][256]
        i = idx - PW2; int n = i >> 8, k = i & 255;
        v = w1[(size_t)k * 128 + n]; th = w1h;
    } else {                    // w_2 [128][64] -> [64][128]
        i = idx - PW3; int n = i >> 7, k = i & 127;
        v = w2[(size_t)k * 64 + n]; th = w2h;
    }
    th[i] = f2h(v);
}

// ---------------- fp16-MFMA GEMM with fused A-transform / attn / BN-stats epilogues -------
// AMODE 0: A fp16 [M][K]. AMODE 1: A f32, cvt in staging. AMODE 2: A f32 + BN + lrelu.
// B: fp16 [N][K] (pre-transposed). BK=32, BM=64. 4 waves 2x2; frags MR=2 x NR=BN/32.
// OF16: C written as fp16.
template<int BN, int AMODE, bool ATTN, bool STATS, bool OF16>
__global__ __launch_bounds__(256) void gemm_f16(
    const void* __restrict__ Ain, const ushort* __restrict__ Bh,
    void* __restrict__ Cout, int M, int N, int K,
    const float* __restrict__ att_s, const float* __restrict__ att_d,
    float* __restrict__ a_src, float* __restrict__ a_dst,
    float* __restrict__ stats,
    const float* __restrict__ bnst, const float* __restrict__ bng,
    const float* __restrict__ bnbe)
{
    constexpr int BM = 64;
    constexpr int MR = 2, NR = BN / 32;
    __shared__ ushort sA[BM][40], sB[BN][40];   // 80B row stride: 2-way bank (free)
    __shared__ float bsc[256], bsh[256];        // BN scale/shift (AMODE 2, K<=256)
    int tid = threadIdx.x;
    int lane = tid & 63, wave = tid >> 6;
    int wr = wave >> 1, wc = wave & 1;
    int bm = blockIdx.y * BM, bn = blockIdx.x * BN;
    int mrow = lane & 15, kb = lane >> 4;

    if constexpr (AMODE == 2) {
        for (int c = tid; c < K; c += 256) {
            float m = bnst[c] * (1.f / NNODES);
            float var = bnst[K + c] * (1.f / NNODES) - m * m;
            float sc = bng[c] * rsqrtf(var + 1e-5f);
            bsc[c] = sc;
            bsh[c] = bnbe[c] - m * sc;
        }
        __syncthreads();
    }

    int ar = tid >> 2, akc = tid & 3;
    int arow = bm + ar;
    bool aval = arow < M;
    size_t aoff = (size_t)(aval ? arow : 0) * K + akc * 8;
    int br, bkc;
    if constexpr (BN == 128) { br = tid >> 1; bkc = (tid & 1) * 2; }
    else { br = tid >> 2; bkc = tid & 3; }
    size_t boff = (size_t)(bn + br) * K + bkc * 8;

    f32x4 acc[MR][NR];
    #pragma unroll
    for (int i = 0; i < MR; ++i)
        #pragma unroll
        for (int j = 0; j < NR; ++j)
            acc[i][j] = (f32x4){0.f, 0.f, 0.f, 0.f};

    for (int k0 = 0; k0 < K; k0 += 32) {
        int4 va;
        if constexpr (AMODE == 0) {
            va = aval ? *(const int4*)((const ushort*)Ain + aoff + k0) : (int4){0, 0, 0, 0};
        } else {
            u16x8 us = (u16x8)0;
            if (aval) {
                const float* ap = (const float*)Ain + aoff + k0;
                float4 f0 = *(const float4*)ap;
                float4 f1 = *(const float4*)(ap + 4);
                float vv[8] = {f0.x, f0.y, f0.z, f0.w, f1.x, f1.y, f1.z, f1.w};
                #pragma unroll
                for (int j = 0; j < 8; ++j) {
                    float v = vv[j];
                    if constexpr (AMODE == 2) {
                        int c = k0 + akc * 8 + j;
                        v = fmaf(v, bsc[c], bsh[c]);
                        v = (v > 0.f) ? v : 0.01f * v;
                    }
                    us[j] = f2h(v);
                }
            }
            va = __builtin_bit_cast(int4, us);
        }
        int4 vb0 = *(const int4*)(Bh + boff + k0);
        int4 vb1;
        if constexpr (BN == 128) vb1 = *(const int4*)(Bh + boff + k0 + 8);
        __syncthreads();
        *(int4*)&sA[ar][akc * 8] = va;
        *(int4*)&sB[br][bkc * 8] = vb0;
        if constexpr (BN == 128) *(int4*)&sB[br][(bkc + 1) * 8] = vb1;
        __syncthreads();

        f16x8 fa[MR], fb[NR];
        #pragma unroll
        for (int fi = 0; fi < MR; ++fi)
            fa[fi] = *(const f16x8*)&sA[wr * 32 + fi * 16 + mrow][kb * 8];
        #pragma unroll
        for (int fj = 0; fj < NR; ++fj)
            fb[fj] = *(const f16x8*)&sB[wc * (BN / 2) + fj * 16 + mrow][kb * 8];
        #pragma unroll
        for (int fi = 0; fi < MR; ++fi)
            #pragma unroll
            for (int fj = 0; fj < NR; ++fj)
                acc[fi][fj] = __builtin_amdgcn_mfma_f32_16x16x32_f16(fa[fi], fb[fj], acc[fi][fj], 0, 0, 0);
    }

    // C write: row = bm + wr*32 + fi*16 + (lane>>4)*4 + r ; col = bn + wc*(BN/2) + fj*16 + mrow
    #pragma unroll
    for (int fi = 0; fi < MR; ++fi) {
        int crow0 = bm + wr * 32 + fi * 16 + (lane >> 4) * 4;
        #pragma unroll
        for (int fj = 0; fj < NR; ++fj) {
            int ccol = bn + wc * (BN / 2) + fj * 16 + mrow;
            #pragma unroll
            for (int r = 0; r < 4; ++r) {
                int row = crow0 + r;
                if (row < M) {
                    if constexpr (OF16)
                        ((ushort*)Cout)[(size_t)row * N + ccol] = f2h(acc[fi][fj][r]);
                    else
                        ((float*)Cout)[(size_t)row * N + ccol] = acc[fi][fj][r];
                }
            }
        }
    }

    if constexpr (ATTN) {
        int hd = bn >> 8;
        float as_v[NR], ad_v[NR];
        #pragma unroll
        for (int fj = 0; fj < NR; ++fj) {
            int c = bn + wc * (BN / 2) + fj * 16 + mrow;
            as_v[fj] = att_s[c];
            ad_v[fj] = att_d[c];
        }
        #pragma unroll
        for (int fi = 0; fi < MR; ++fi)
            #pragma unroll
            for (int r = 0; r < 4; ++r) {
                float ss = 0.f, sd = 0.f;
                #pragma unroll
                for (int fj = 0; fj < NR; ++fj) {
                    float v = acc[fi][fj][r];
                    ss = fmaf(v, as_v[fj], ss);
                    sd = fmaf(v, ad_v[fj], sd);
                }
                #pragma unroll
                for (int off = 1; off < 16; off <<= 1) {
                    ss += __shfl_xor(ss, off);
                    sd += __shfl_xor(sd, off);
                }
                if (mrow == 0) {
                    int row = bm + wr * 32 + fi * 16 + (lane >> 4) * 4 + r;
                    if (row < M) {
                        atomicAdd(&a_src[2 * row + hd], ss);
                        atomicAdd(&a_dst[2 * row + hd], sd);
                    }
                }
            }
    }

    if constexpr (STATS) {
        #pragma unroll
        for (int fj = 0; fj < NR; ++fj) {
            float s = 0.f, s2 = 0.f;
            #pragma unroll
            for (int fi = 0; fi < MR; ++fi)
                #pragma unroll
                for (int r = 0; r < 4; ++r) {
                    float v = acc[fi][fj][r];
                    s += v;
                    s2 = fmaf(v, v, s2);
                }
            s  += __shfl_xor(s, 16);  s  += __shfl_xor(s, 32);
            s2 += __shfl_xor(s2, 16); s2 += __shfl_xor(s2, 32);
            if (lane < 16) {
                int c = bn + wc * (BN / 2) + fj * 16 + lane;
                atomicAdd(&stats[c], s);
                atomicAdd(&stats[N + c], s2);
            }
        }
    }
}

// ---------------- scatter edges into fixed-stride buckets; p = exp(lrelu(e)) ----------
__global__ __launch_bounds__(256) void scatter_kernel(const int* __restrict__ ei,
    const float* __restrict__ a_src, const float* __restrict__ a_dst,
    int* __restrict__ cnt, int* __restrict__ esrc,
    float* __restrict__ p0, float* __restrict__ p1)
{
    int e = blockIdx.x * 256 + threadIdx.x;
    if (e >= ETOT) return;
    int s, d;
    if (e < NEDGES) { s = ei[e]; d = ei[NEDGES + e]; } else { s = d = e - NEDGES; }
    int pos = atomicAdd(&cnt[d], 1);
    if (pos >= MAXDEG) return;   // statistically impossible for this graph
    int slot = d * MAXDEG + pos;
    esrc[slot] = s;
    float e0 = a_src[2 * s] + a_dst[2 * d];
    e0 = (e0 > 0.f) ? e0 : 0.2f * e0;
    float e1 = a_src[2 * s + 1] + a_dst[2 * d + 1];
    e1 = (e1 > 0.f) ? e1 : 0.2f * e1;
    p0[slot] = expf(e0);
    p1[slot] = expf(e1);
}

// ---------------- per-node aggregation (fp16 h) -> lrelu -> fp16 y ----------------
// 128 threads: thread t owns features [4t,4t+4); t<64 = head0 (p0), t>=64 = head1 (p1).
__global__ __launch_bounds__(128) void aggregate_kernel(const ushort* __restrict__ h,
    const int* __restrict__ cnt, const int* __restrict__ esrc,
    const float* __restrict__ p0, const float* __restrict__ p1,
    const float* __restrict__ b_conv, ushort* __restrict__ yh)
{
    int n = blockIdx.x, t = threadIdx.x;
    int len = cnt[n]; if (len > MAXDEG) len = MAXDEG;
    int base = n * MAXDEG;
    const float* pp = (t < 64) ? p0 : p1;
    float a0 = 0.f, a1 = 0.f, a2 = 0.f, a3 = 0.f;
    float den = 0.f;
    for (int k = 0; k < len; ++k) {
        int src = esrc[base + k];
        float q = pp[base + k];
        ushort4 hv = ((const ushort4*)(h + (size_t)src * HD))[t];
        a0 = fmaf(q, h2f(hv.x), a0);
        a1 = fmaf(q, h2f(hv.y), a1);
        a2 = fmaf(q, h2f(hv.z), a2);
        a3 = fmaf(q, h2f(hv.w), a3);
        den += q;
    }
    float4 bc = *(const float4*)(b_conv + t * 4);
    float inv = 1.f / den;
    float o[4] = { a0 * inv + bc.x, a1 * inv + bc.y, a2 * inv + bc.z, a3 * inv + bc.w };
    ushort4 hq;
    float v;
    v = (o[0] > 0.f) ? o[0] : 0.01f * o[0]; hq.x = f2h(v);
    v = (o[1] > 0.f) ? o[1] : 0.01f * o[1]; hq.y = f2h(v);
    v = (o[2] > 0.f) ? o[2] : 0.01f * o[2]; hq.z = f2h(v);
    v = (o[3] > 0.f) ? o[3] : 0.01f * o[3]; hq.w = f2h(v);
    ((ushort4*)(yh + (size_t)n * HD))[t] = hq;
}

// ---------------- BN(64) + lrelu + dense3 fused -> y3 ----------------
__global__ __launch_bounds__(256) void bn_dense3(const float* __restrict__ z2,
    const float* __restrict__ st, const float* __restrict__ g, const float* __restrict__ beta,
    const float* __restrict__ w3, const float* __restrict__ b3, float* __restrict__ y3)
{
    __shared__ float wsm[192], msm[64], rsm[64], gsm[64], bsm[64];
    int t = threadIdx.x;
    if (t < 192) wsm[t] = w3[t];
    if (t < 64) {
        float m = st[t] * (1.f / NNODES);
        float v = st[64 + t] * (1.f / NNODES) - m * m;
        msm[t] = m; rsm[t] = rsqrtf(v + 1e-5f);
        gsm[t] = g[t]; bsm[t] = beta[t];
    }
    __syncthreads();
    int n = blockIdx.x * 256 + t;
    if (n >= NNODES) return;
    const float* zr = z2 + (size_t)n * 64;
    float o0 = b3[0], o1 = b3[1], o2 = b3[2];
    #pragma unroll
    for (int c = 0; c < 64; ++c) {
        float xv = zr[c];
        xv = gsm[c] * (xv - msm[c]) * rsm[c] + bsm[c];
        xv = (xv > 0.f) ? xv : 0.01f * xv;
        o0 = fmaf(xv, wsm[3 * c],     o0);
        o1 = fmaf(xv, wsm[3 * c + 1], o1);
        o2 = fmaf(xv, wsm[3 * c + 2], o2);
    }
    y3[3 * n] = o0; y3[3 * n + 1] = o1; y3[3 * n + 2] = o2;
}

// ---------------- pairwise euclidean distances [N,N], 4 cols/thread, NT f32x4 stores ----
__global__ __launch_bounds__(256) void dist_kernel(const float* __restrict__ y3, float* __restrict__ out)
{
    int j0 = (blockIdx.x * 256 + threadIdx.x) * 4;
    int i0 = blockIdx.y * 64;
    if (j0 >= NNODES) return;
    const float4* yp = (const float4*)(y3 + 3 * j0);
    float4 q0 = yp[0], q1 = yp[1], q2 = yp[2];
    float xj[4] = {q0.x, q0.w, q1.z, q2.y};
    float yj[4] = {q0.y, q1.x, q1.w, q2.z};
    float zj[4] = {q0.z, q1.y, q2.x, q2.w};
    int iend = (i0 + 64 < NNODES) ? (i0 + 64) : NNODES;
    for (int i = i0; i < iend; ++i) {
        float xi = y3[3 * i], yi = y3[3 * i + 1], zi = y3[3 * i + 2];
        f32x4 dv;
        #pragma unroll
        for (int u = 0; u < 4; ++u) {
            float dx = xi - xj[u], dy = yi - yj[u], dz = zi - zj[u];
            float d2 = fmaf(dx, dx, fmaf(dy, dy, dz * dz));
            dv[u] = (d2 > 1e-12f) ? sqrtf(d2) : 0.f;
        }
        __builtin_nontemporal_store(dv, (f32x4*)(out + (size_t)i * NNODES + j0));
    }
}

extern "C" void kernel_launch(void* const* d_in, const int* in_sizes, int n_in,
                              void* d_out, int out_size, void* d_ws, size_t ws_size,
                              hipStream_t stream)
{
    (void)in_sizes; (void)n_in; (void)out_size; (void)ws_size;
    const float* x      = (const float*)d_in[0];
    const int*   ei     = (const int*)  d_in[1];
    const float* w_conv = (const float*)d_in[2];
    const float* att_s  = (const float*)d_in[3];
    const float* att_d  = (const float*)d_in[4];
    const float* b_conv = (const float*)d_in[5];
    const float* w_a  = (const float*)d_in[6];
    const float* g_a  = (const float*)d_in[8];
    const float* be_a = (const float*)d_in[9];
    const float* w_1  = (const float*)d_in[10];
    const float* g_1  = (const float*)d_in[12];
    const float* be_1 = (const float*)d_in[13];
    const float* w_2  = (const float*)d_in[14];
    const float* g_2  = (const float*)d_in[16];
    const float* be_2 = (const float*)d_in[17];
    const float* w_3  = (const float*)d_in[18];
    const float* b_3  = (const float*)d_in[19];

    char* ws = (char*)d_ws;
    size_t off = 0;
    auto take = [&](size_t bytes) {
        char* p = ws + off;
        off = (off + bytes + 255) & ~(size_t)255;
        return p;
    };
    ushort* h   = (ushort*)take((size_t)NNODES * HD * 2);      // fp16 h
    ushort* yh  = (ushort*)take((size_t)NNODES * HD * 2);      // fp16 y
    float* z_a  = (float*)take((size_t)NNODES * 256 * 4);
    float* z_1  = (float*)take((size_t)NNODES * 128 * 4);
    float* z_2  = (float*)take((size_t)NNODES * 64 * 4);
    float* y3   = (float*)take((size_t)NNODES * 3 * 4);
    ushort* wch = (ushort*)take((size_t)512 * 512 * 2);
    ushort* wah = (ushort*)take((size_t)256 * 512 * 2);
    ushort* w1h = (ushort*)take((size_t)128 * 256 * 2);
    ushort* w2h = (ushort*)take((size_t)64 * 128 * 2);
    int*   esrc = (int*)  take((size_t)NNODES * MAXDEG * 4);
    float* p0   = (float*)take((size_t)NNODES * MAXDEG * 4);
    float* p1   = (float*)take((size_t)NNODES * MAXDEG * 4);
    // zeroed block: cnt, stats x3, a_src, a_dst
    const size_t ZB = 40000 + 2048 + 1024 + 512 + 80000 + 80000;
    char*  zblk = take(ZB);
    int*   cnt  = (int*)(zblk);
    float* stA  = (float*)(zblk + 40000);
    float* st1  = (float*)(zblk + 42048);
    float* st2  = (float*)(zblk + 43072);
    float* a_src= (float*)(zblk + 43584);
    float* a_dst= (float*)(zblk + 123584);

    hipMemsetAsync(zblk, 0, ZB, stream);

    dim3 b256(256), b128(128);
    const int MT = (NNODES + 63) / 64;   // 157

    // weights -> fp16 transposed
    prep_kernel<<<dim3((PW4 + 255) / 256), b256, 0, stream>>>(
        w_conv, wch, w_a, wah, w_1, w1h, w_2, w2h);

    // h = x @ w_conv (fp16 out, x converted in staging), fused attn coefficients
    gemm_f16<128, 1, true, false, true><<<dim3(HD / 128, MT), b256, 0, stream>>>(
        x, wch, h, NNODES, HD, FINF, att_s, att_d, a_src, a_dst, nullptr,
        nullptr, nullptr, nullptr);

    scatter_kernel<<<dim3((ETOT + 255) / 256), b256, 0, stream>>>(
        ei, a_src, a_dst, cnt, esrc, p0, p1);

    aggregate_kernel<<<dim3(NNODES), b128, 0, stream>>>(
        h, cnt, esrc, p0, p1, b_conv, yh);

    // densea 512->256 (A = y fp16), stats fused
    gemm_f16<128, 0, false, true, false><<<dim3(256 / 128, MT), b256, 0, stream>>>(
        yh, wah, z_a, NNODES, 256, 512, nullptr, nullptr, nullptr, nullptr, stA,
        nullptr, nullptr, nullptr);

    // dense1 256->128 (A = BN(z_a)+lrelu in staging), stats fused
    gemm_f16<64, 2, false, true, false><<<dim3(128 / 64, MT), b256, 0, stream>>>(
        z_a, w1h, z_1, NNODES, 128, 256, nullptr, nullptr, nullptr, nullptr, st1,
        stA, g_a, be_a);

    // dense2 128->64 (A = BN(z_1)+lrelu in staging), stats fused
    gemm_f16<64, 2, false, true, false><<<dim3(64 / 64, MT), b256, 0, stream>>>(
        z_1, w2h, z_2, NNODES, 64, 128, nullptr, nullptr, nullptr, nullptr, st2,
        st1, g_1, be_1);

    // BN + lrelu + dense3 fused
    bn_dense3<<<dim3((NNODES + 255) / 256), b256, 0, stream>>>(z_2, st2, g_2, be_2, w_3, b_3, y3);

    // pairwise distances
    dist_kernel<<<dim3((NNODES + 1023) / 1024, (NNODES + 63) / 64), b256, 0, stream>>>(y3, (float*)d_out);
}